// Round 8
// baseline (513.638 us; speedup 1.0000x reference)
//
#include <hip/hip_runtime.h>

// NLBlock fused pipeline for MI355X (gfx950). ALL I/O IS FP32.
// Algebra: logits = x.G.lfb^T + v[s], G = Wth^T.Wph (softmax drops per-row
// constants). Split-precision hi/lo bf16 through G, y, lfb for the x32 logits.
// R16: gemm8 = R13 2-barrier 256x256x64 schedule (best measured) switched to
// v_mfma_f32_32x32x16_bf16 (2495 vs 2176 TF ceiling, -17% matrix-pipe time;
// same LDS bytes). Lane map: lr=l&31,kh=l>>5; frag=short8 @ row=tile*32+lr,
// k-chunk (ks*2+kh)^(lr&7). C/D: col=lane&31,row=(r&3)+8(r>>2)+4kh (m74/m101).
// Ledger fix vs R13: END vmcnt(4) (not 8) so A(t+1) is landed before TOP of
// t+1 reads it. Other GEMMs on gemm_bt (128x128x64, XOR-swizzle, XCD decode).

#define BM 128
#define BN 128
#define BK 64

typedef __attribute__((ext_vector_type(8))) short short8;
typedef __attribute__((ext_vector_type(4))) float f32x4;
typedef __attribute__((ext_vector_type(16))) float f32x16;
typedef __attribute__((ext_vector_type(4))) unsigned short us4;

enum { MODE_SPLIT = 0, MODE_TRANS = 1, MODE_F32 = 2, MODE_FINAL = 3 };

__device__ __forceinline__ float b2f(unsigned short u) {
  union { unsigned int i; float f; } x;
  x.i = ((unsigned int)u) << 16;
  return x.f;
}
__device__ __forceinline__ unsigned short f2b(float f) {
  unsigned int u = __float_as_uint(f);
  unsigned int r = (u + 0x7FFFu + ((u >> 16) & 1u)) >> 16;
  return (unsigned short)r;
}

__device__ __forceinline__ void async_cp16(const unsigned short* g,
                                           unsigned short* l) {
  __builtin_amdgcn_global_load_lds(
      (const __attribute__((address_space(1))) void*)g,
      (__attribute__((address_space(3))) void*)l, 16, 0, 0);
}

// Fused: blocks [0,Ms): lfb row -> ls hi/lo + v[row]=dot(lfb[row],g).
//        blocks [Ms,Ms+Mt): x row -> xs hi/lo.
__global__ __launch_bounds__(256) void split_xlfb(
    const float* __restrict__ lfb, const float* __restrict__ x,
    const float* __restrict__ g, unsigned short* __restrict__ ls,
    unsigned short* __restrict__ xs, float* __restrict__ v, int Ms) {
  const int id = blockIdx.x;
  const int t = threadIdx.x;
  const int c = t * 4;
  if (id < Ms) {
    __shared__ float red[4];
    f32x4 xv = *(const f32x4*)&lfb[(size_t)id * 1024 + c];
    f32x4 gg = *(const f32x4*)&g[c];
    us4 hi, lo;
    float s = 0.f;
#pragma unroll
    for (int i = 0; i < 4; ++i) {
      hi[i] = f2b(xv[i]);
      lo[i] = f2b(xv[i] - b2f(hi[i]));
      s += xv[i] * gg[i];
    }
    *(us4*)&ls[(size_t)id * 2048 + c] = hi;
    *(us4*)&ls[(size_t)id * 2048 + 1024 + c] = lo;
    for (int o = 32; o; o >>= 1) s += __shfl_xor(s, o, 64);
    if ((t & 63) == 0) red[t >> 6] = s;
    __syncthreads();
    if (t == 0) v[id] = red[0] + red[1] + red[2] + red[3];
  } else {
    const int r = id - Ms;
    f32x4 xv = *(const f32x4*)&x[(size_t)r * 1024 + c];
    us4 hi, lo;
#pragma unroll
    for (int i = 0; i < 4; ++i) {
      hi[i] = f2b(xv[i]);
      lo[i] = f2b(xv[i] - b2f(hi[i]));
    }
    *(us4*)&xs[(size_t)r * 2048 + c] = hi;
    *(us4*)&xs[(size_t)r * 2048 + 1024 + c] = lo;
  }
}

// two fp32->bf16 conversions in one launch (1 MiB elems each)
__global__ __launch_bounds__(256) void cvt2_bf16(const float* __restrict__ s0,
                                                 unsigned short* __restrict__ d0,
                                                 const float* __restrict__ s1,
                                                 unsigned short* __restrict__ d1) {
  int b = blockIdx.x;
  const float* src = (b < 1024) ? s0 : s1;
  unsigned short* dst = (b < 1024) ? d0 : d1;
  int g = (b & 1023) * 256 + threadIdx.x;
  f32x4 v = *(const f32x4*)&src[g * 4];
  us4 o;
#pragma unroll
  for (int i = 0; i < 4; ++i) o[i] = f2b(v[i]);
  *(us4*)&dst[(size_t)g * 4] = o;
}

// Both weight transposes in one launch: W [1024][1024] fp32 -> T [c][2048]
// bf16 hi|lo with T[c][o]=split(W[o][c]).
__global__ __launch_bounds__(256) void transpose_split2(
    const float* __restrict__ W0, unsigned short* __restrict__ T0,
    const float* __restrict__ W1, unsigned short* __restrict__ T1) {
  __shared__ float tile[64][65];
  const int sel = blockIdx.y >> 4;
  const float* W = sel ? W1 : W0;
  unsigned short* T = sel ? T1 : T0;
  const int bo = (blockIdx.y & 15) * 64;
  const int bc = blockIdx.x * 64;
  const int t = threadIdx.x;
  const int tr = t >> 4;
  const int tc = (t & 15) * 4;
#pragma unroll
  for (int i = 0; i < 4; ++i) {
    f32x4 v = *(const f32x4*)&W[(size_t)(bo + tr + 16 * i) * 1024 + bc + tc];
#pragma unroll
    for (int j = 0; j < 4; ++j) tile[tr + 16 * i][tc + j] = v[j];
  }
  __syncthreads();
#pragma unroll
  for (int i = 0; i < 4; ++i) {
    const int c = bc + tr + 16 * i;
    us4 hi, lo;
#pragma unroll
    for (int j = 0; j < 4; ++j) {
      float v = tile[tc + j][tr + 16 * i];
      hi[j] = f2b(v);
      lo[j] = f2b(v - b2f(hi[j]));
    }
    *(us4*)&T[(size_t)c * 2048 + bo + tc] = hi;
    *(us4*)&T[(size_t)c * 2048 + 1024 + bo + tc] = lo;
  }
}

// g[d] = sum_o Wph[o][d]*bth[o], from tB (= Wph^T split hi/lo). wave per d.
__global__ __launch_bounds__(256) void make_g(
    const unsigned short* __restrict__ tB, const float* __restrict__ bth,
    float* __restrict__ g) {
  const int d = blockIdx.x * 4 + (threadIdx.x >> 6);
  const int lane = threadIdx.x & 63;
  float s = 0.f;
#pragma unroll
  for (int i = 0; i < 4; ++i) {
    const int o0 = lane * 4 + i * 256;
    us4 h = *(const us4*)&tB[(size_t)d * 2048 + o0];
    us4 lo = *(const us4*)&tB[(size_t)d * 2048 + 1024 + o0];
    f32x4 bb = *(const f32x4*)&bth[o0];
#pragma unroll
    for (int j = 0; j < 4; ++j) s += (b2f(h[j]) + b2f(lo[j])) * bb[j];
  }
  for (int o = 32; o; o >>= 1) s += __shfl_xor(s, o, 64);
  if (lane == 0) g[d] = s;
}

// Gs[d][c](hi|lo) = split(sum_z P[z][d][c])   (split-K reduce for G)
__global__ __launch_bounds__(256) void reduce_g(const float* __restrict__ P,
                                                unsigned short* __restrict__ Gs) {
  const int d = blockIdx.x;
  const int c = threadIdx.x * 4;
  f32x4 s = *(const f32x4*)&P[(size_t)d * 1024 + c];
#pragma unroll
  for (int z = 1; z < 8; ++z) {
    f32x4 p = *(const f32x4*)&P[(size_t)z * 1048576 + (size_t)d * 1024 + c];
#pragma unroll
    for (int i = 0; i < 4; ++i) s[i] += p[i];
  }
  us4 hi, lo;
#pragma unroll
  for (int i = 0; i < 4; ++i) {
    hi[i] = f2b(s[i]);
    lo[i] = f2b(s[i] - b2f(hi[i]));
  }
  *(us4*)&Gs[(size_t)d * 2048 + c] = hi;
  *(us4*)&Gs[(size_t)d * 2048 + 1024 + c] = lo;
}

// swz=0: plain (n = id%NBk, m = (id/NBk)%MBk, z = id/(NBk*MBk))
// swz=1: z-per-XCD (z = id&7, r=id>>3, m = r%mbx, n = r/mbx)
// swz=2: m-slab-per-XCD (z=0, m = (id&7)*mbx + r%mbx, n = r/mbx)
// kzoff!=0: z indexes a K-chunk (global k = k0 + z*kzoff; A/B bases unshifted)
template <int MODE>
__global__ __launch_bounds__(256, 4) void gemm_bt(
    const unsigned short* __restrict__ A, const unsigned short* __restrict__ B,
    void* __restrict__ Cout, const float* __restrict__ bias,
    const float* __restrict__ resid, int M, int N, int K, int lda, int ldb,
    int ldc, long long sA, long long sB, long long sC, long long sBias,
    int awrap, int awoff, int bwrap, int bwoff, int NBk, int MBk, int mbx,
    int swz, int kzoff) {
  __shared__ __align__(16) unsigned short As[BM * BK];
  __shared__ __align__(16) unsigned short Bs[BN * BK];

  const int tid = threadIdx.x;
  const int l = tid & 63;
  const int w = tid >> 6;
  const int wm = w >> 1, wn = w & 1;
  const int ln = l & 15, lq = l >> 4;

  int bmi, bni, bzi;
  {
    const int id = blockIdx.x;
    if (swz == 1) {
      bzi = id & 7;
      const int r = id >> 3;
      bmi = r % mbx;
      bni = r / mbx;
    } else if (swz == 2) {
      bzi = 0;
      const int r = id >> 3;
      bmi = (id & 7) * mbx + r % mbx;
      bni = r / mbx;
    } else {
      bni = id % NBk;
      const int rem = id / NBk;
      bmi = rem % MBk;
      bzi = rem / MBk;
    }
  }
  const int bm = bmi * BM;
  const int bn = bni * BN;
  const unsigned short* Ab = A + (size_t)bzi * (size_t)sA;
  const unsigned short* Bb = B + (size_t)bzi * (size_t)sB;
  const float* bz = bias ? bias + (size_t)bzi * (size_t)sBias : nullptr;
  const int kbase = bzi * kzoff;

  const int arow = tid >> 3;
  // Swizzled fetch: lane (rr=l>>3, cc=l&7) fetches k-chunk cc^rr; LDS chunk pc
  // of row r holds k-chunk pc^(r&7). Zero bank conflicts on ds_read_b128.
  const int acol = (((tid & 7) ^ ((tid >> 3) & 7)) * 8);
  const int ldsbase = (tid & 0xC0) * 8;

  f32x4 acc[4][4];
#pragma unroll
  for (int i = 0; i < 4; ++i)
#pragma unroll
    for (int j = 0; j < 4; ++j) acc[i][j] = (f32x4){0.f, 0.f, 0.f, 0.f};

  const int sw = ln & 7;

  for (int k0 = 0; k0 < K; k0 += BK) {
    const int kg = k0 + kbase;
    const int ka = (kg < awrap) ? kg : kg - awoff;
    const int kb = (kg < bwrap) ? kg : kg - bwoff;
#pragma unroll
    for (int it = 0; it < 4; ++it) {
      const int r = it * 32 + arow;
      async_cp16(Ab + (size_t)(bm + r) * lda + ka + acol,
                 &As[it * 2048 + ldsbase]);
    }
#pragma unroll
    for (int it = 0; it < 4; ++it) {
      const int r = it * 32 + arow;
      async_cp16(Bb + (size_t)(bn + r) * ldb + kb + acol,
                 &Bs[it * 2048 + ldsbase]);
    }
    __syncthreads();

#pragma unroll
    for (int ks = 0; ks < 2; ++ks) {
      short8 a[4], b[4];
      const int kof = ((ks * 4 + lq) ^ sw) * 8;
#pragma unroll
      for (int i = 0; i < 4; ++i)
        a[i] = *(const short8*)&As[(wm * 64 + i * 16 + ln) * BK + kof];
#pragma unroll
      for (int j = 0; j < 4; ++j)
        b[j] = *(const short8*)&Bs[(wn * 64 + j * 16 + ln) * BK + kof];
#pragma unroll
      for (int i = 0; i < 4; ++i)
#pragma unroll
        for (int j = 0; j < 4; ++j)
          acc[i][j] = __builtin_amdgcn_mfma_f32_16x16x32_bf16(a[i], b[j],
                                                              acc[i][j], 0, 0, 0);
    }
    __syncthreads();
  }

  float* Cf = (float*)Cout + (size_t)bzi * (size_t)sC;
  unsigned short* Cb = (unsigned short*)Cout + (size_t)bzi * (size_t)sC;

  if constexpr (MODE == MODE_TRANS) {
#pragma unroll
    for (int i = 0; i < 4; ++i) {
      const int gm0 = bm + wm * 64 + i * 16 + lq * 4;
      const int bt = gm0 >> 11;
      const int sr = gm0 & 2047;
#pragma unroll
      for (int j = 0; j < 4; ++j) {
        const int gn = bn + wn * 64 + j * 16 + ln;
        const float bv2 = (bz != nullptr) ? bz[gn] : 0.f;
        us4 o;
#pragma unroll
        for (int r = 0; r < 4; ++r) o[r] = f2b(acc[i][j][r] + bv2);
        *(us4*)&Cb[(size_t)bt * 2097152 + (size_t)gn * 2048 + sr] = o;
      }
    }
  } else {
#pragma unroll
    for (int j = 0; j < 4; ++j) {
      const int gn = bn + wn * 64 + j * 16 + ln;
      const float bv2 = (bz != nullptr) ? bz[gn] : 0.f;
#pragma unroll
      for (int i = 0; i < 4; ++i) {
        const int gm0 = bm + wm * 64 + i * 16 + lq * 4;
#pragma unroll
        for (int r = 0; r < 4; ++r) {
          const int gm = gm0 + r;
          const float v = acc[i][j][r] + bv2;
          if constexpr (MODE == MODE_SPLIT) {
            unsigned short hi = f2b(v);
            Cb[(size_t)gm * ldc + gn] = hi;
            Cb[(size_t)gm * ldc + gn + (ldc >> 1)] = f2b(v - b2f(hi));
          } else if constexpr (MODE == MODE_F32) {
            Cf[(size_t)gm * ldc + gn] = v;
          } else if constexpr (MODE == MODE_FINAL) {
            const size_t idx = (size_t)gm * ldc + gn;
            Cf[idx] = v + resid[idx];
          }
        }
      }
    }
  }
}

// ---- gemm8: 256x256x64 tile, 512 threads (8 waves, wm=w>>2 A-half, wn=w&3
// B-quarter), 32x32x16 MFMA fragments (acc[4][2] f32x16). 2-barrier schedule:
// TOP[24 ds_reads + stageA(t+1)->p^1] MFMA ks0-1 | lgkm(0) MID bar
// stageB(t+2)->p MFMA ks2-3 vmcnt(4) END bar.
// LDS A[2][2][8192]+B[2][2][8192] = 128 KiB (same staging as before).
template <int MODE>
__global__ __launch_bounds__(512, 1) void gemm8(
    const unsigned short* __restrict__ A, const unsigned short* __restrict__ B,
    void* __restrict__ Cout, const float* __restrict__ bias, int M, int N,
    int K, int lda, int ldb, int ldc, long long sA, long long sB, long long sC,
    long long sBias, int awrap, int awoff, int bwrap, int bwoff, int NBk,
    int MBk, int mbx, int swz) {
  __shared__ __align__(16) unsigned short Abuf[2][2][8192];
  __shared__ __align__(16) unsigned short Bbuf[2][2][8192];

  const int tid = threadIdx.x;
  const int l = tid & 63;
  const int w = tid >> 6;        // 0..7
  const int wm = w >> 2;         // 0..1 : A half (128 rows)
  const int wn = w & 3;          // 0..3 : B quarter (64 cols)
  const int lr = l & 31;         // 32x32 row/col lane
  const int kh = l >> 5;         // k-half within frag

  int bmi, bni, bzi;
  {
    const int id = blockIdx.x;
    if (swz == 1) {
      bzi = id & 7;
      const int r = id >> 3;
      bmi = r % mbx;
      bni = r / mbx;
    } else if (swz == 2) {
      bzi = 0;
      const int r = id >> 3;
      bmi = (id & 7) * mbx + r % mbx;
      bni = r / mbx;
    } else {
      bni = id % NBk;
      const int rem = id / NBk;
      bmi = rem % MBk;
      bzi = rem / MBk;
    }
  }
  const int bm = bmi * 256;
  const int bn = bni * 256;
  const unsigned short* Ab = A + (size_t)bzi * (size_t)sA;
  const unsigned short* Bb = B + (size_t)bzi * (size_t)sB;
  const float* bz = bias ? bias + (size_t)bzi * (size_t)sBias : nullptr;

  // staging geometry (unchanged): thread covers chunk c=j*512+tid of a 128x64
  // half-tile; row=c>>3, pc=c&7, source k-chunk = pc^(row&7).
  const int srow = tid >> 3;                                // 0..63
  const int schk = ((tid & 7) ^ ((tid >> 3) & 7)) * 8;      // elem offset
  const int sdst0 = (tid & 448) * 8;                        // wave-uniform base

  auto stageA = [&](int d, int kk) {
#pragma unroll
    for (int half = 0; half < 2; ++half)
#pragma unroll
      for (int j = 0; j < 2; ++j)
        async_cp16(Ab + (size_t)(bm + half * 128 + srow + j * 64) * lda + kk +
                       schk,
                   &Abuf[d][half][sdst0 + j * 4096]);
  };
  auto stageB = [&](int d, int kk) {
#pragma unroll
    for (int half = 0; half < 2; ++half)
#pragma unroll
      for (int j = 0; j < 2; ++j)
        async_cp16(Bb + (size_t)(bn + half * 128 + srow + j * 64) * ldb + kk +
                       schk,
                   &Bbuf[d][half][sdst0 + j * 4096]);
  };
  auto wrapA = [&](int kg) { return (kg < awrap) ? kg : kg - awoff; };
  auto wrapB = [&](int kg) { return (kg < bwrap) ? kg : kg - bwoff; };

  // frag read: tile = 32-row group within the 128-row half; k-chunk
  // (ks*2+kh) ^ (lr&7), row = tile*32 + lr. 16B aligned.
  auto ldfrag = [&](const unsigned short* Lb, int tile, int ks) {
    return *(const short8*)&Lb[(tile * 32 + lr) * 64 +
                               (((ks * 2 + kh) ^ (lr & 7)) * 8)];
  };

  f32x16 acc[4][2];
#pragma unroll
  for (int i = 0; i < 4; ++i)
#pragma unroll
    for (int j = 0; j < 2; ++j)
#pragma unroll
      for (int r = 0; r < 16; ++r) acc[i][j][r] = 0.f;

  const int nt = K >> 6;

  // prologue: A(0),B(0)->buf0 (8/thread), B(1)->buf1 (4/thread). vmcnt(4):
  // A0,B0 landed; B1 in flight.
  stageA(0, wrapA(0));
  stageB(0, wrapB(0));
  if (nt > 1) {
    stageB(1, wrapB(64));
    asm volatile("s_waitcnt vmcnt(4)" : : : "memory");
  } else {
    asm volatile("s_waitcnt vmcnt(0)" : : : "memory");
  }
  __builtin_amdgcn_sched_barrier(0);
  __builtin_amdgcn_s_barrier();

  short8 a[4][4], b[2][4];
  const int btile0 = (wn & 1) * 2;   // 32-col tile base within B-half
  const int bhalf = wn >> 1;

  for (int t = 0; t < nt; ++t) {
    const int p = t & 1;
    const unsigned short* LA = &Abuf[p][wm][0];
    const unsigned short* LB = &Bbuf[p][bhalf][0];
    // TOP: all 24 reads, ks-major so early MFMAs' operands arrive first;
    // stage A(t+1) cross-buf (readers retired at t-1 MID lgkm(0)+barrier).
#pragma unroll
    for (int ks = 0; ks < 4; ++ks) {
#pragma unroll
      for (int mi = 0; mi < 4; ++mi) a[mi][ks] = ldfrag(LA, mi, ks);
#pragma unroll
      for (int ni = 0; ni < 2; ++ni) b[ni][ks] = ldfrag(LB, btile0 + ni, ks);
    }
    if (t + 1 < nt) stageA(p ^ 1, wrapA((t + 1) * 64));
    // MFMA ks0-1 (compiler paces lgkmcnt; later reads drain under these)
    __builtin_amdgcn_s_setprio(1);
#pragma unroll
    for (int ks = 0; ks < 2; ++ks)
#pragma unroll
      for (int mi = 0; mi < 4; ++mi)
#pragma unroll
        for (int ni = 0; ni < 2; ++ni)
          acc[mi][ni] = __builtin_amdgcn_mfma_f32_32x32x16_bf16(
              a[mi][ks], b[ni][ks], acc[mi][ni], 0, 0, 0);
    __builtin_amdgcn_s_setprio(0);
    // MID: all buf-p reads retired chip-wide -> B[p] reusable
    asm volatile("s_waitcnt lgkmcnt(0)" : : : "memory");
    __builtin_amdgcn_s_barrier();
    if (t + 2 < nt) stageB(p, wrapB((t + 2) * 64));
    __builtin_amdgcn_s_setprio(1);
#pragma unroll
    for (int ks = 2; ks < 4; ++ks)
#pragma unroll
      for (int mi = 0; mi < 4; ++mi)
#pragma unroll
        for (int ni = 0; ni < 2; ++ni)
          acc[mi][ni] = __builtin_amdgcn_mfma_f32_32x32x16_bf16(
              a[mi][ks], b[ni][ks], acc[mi][ni], 0, 0, 0);
    __builtin_amdgcn_s_setprio(0);
    // END vmcnt(4): keep only B(t+2) in flight; A(t+1) (and B(t+1)) landed
    // before next TOP reads them.
    if (t + 2 < nt) {
      asm volatile("s_waitcnt vmcnt(4)" : : : "memory");
    } else {
      asm volatile("s_waitcnt vmcnt(0)" : : : "memory");
    }
    __builtin_amdgcn_sched_barrier(0);
    __builtin_amdgcn_s_barrier();
  }

  float* Cf = (float*)Cout + (size_t)bzi * (size_t)sC;
  unsigned short* Cb = (unsigned short*)Cout;

  // C/D 32x32 layout: col = lane&31, row = (r&3) + 8*(r>>2) + 4*kh.
  if constexpr (MODE == MODE_TRANS) {
#pragma unroll
    for (int mi = 0; mi < 4; ++mi) {
      const int gm0 = bm + wm * 128 + mi * 32;
#pragma unroll
      for (int ni = 0; ni < 2; ++ni) {
        const int gn = bn + wn * 64 + ni * 32 + lr;
        const float bv2 = (bz != nullptr) ? bz[gn] : 0.f;
#pragma unroll
        for (int q = 0; q < 4; ++q) {
          const int gm = gm0 + 8 * q + 4 * kh;
          const int bt = gm >> 11;
          const int sr = gm & 2047;
          us4 o;
#pragma unroll
          for (int j = 0; j < 4; ++j) o[j] = f2b(acc[mi][ni][4 * q + j] + bv2);
          *(us4*)&Cb[(size_t)bt * 2097152 + (size_t)gn * 2048 + sr] = o;
        }
      }
    }
  } else {  // MODE_F32
#pragma unroll
    for (int ni = 0; ni < 2; ++ni) {
      const int gn = bn + wn * 64 + ni * 32 + lr;
      const float bv2 = (bz != nullptr) ? bz[gn] : 0.f;
#pragma unroll
      for (int mi = 0; mi < 4; ++mi) {
        const int gm0 = bm + wm * 128 + mi * 32;
#pragma unroll
        for (int r = 0; r < 16; ++r) {
          const int gm = gm0 + (r & 3) + 8 * (r >> 2) + 4 * kh;
          Cf[(size_t)gm * ldc + gn] = acc[mi][ni][r] + bv2;
        }
      }
    }
  }
}

// softmax over 2048 fp32 cols, scale 32 -> bf16 attn (compact, stride 2048)
__global__ __launch_bounds__(256) void softmax_rows(
    const float* __restrict__ logit, unsigned short* __restrict__ attn) {
  const int row = blockIdx.x;
  const float* L = logit + (size_t)row * 2048;
  unsigned short* O = attn + (size_t)row * 2048;
  const int t = threadIdx.x;
  __shared__ float red[8];

  f32x4 v0 = *(const f32x4*)&L[t * 4];
  f32x4 v1 = *(const f32x4*)&L[t * 4 + 1024];
  float m = fmaxf(fmaxf(fmaxf(v0[0], v0[1]), fmaxf(v0[2], v0[3])),
                  fmaxf(fmaxf(v1[0], v1[1]), fmaxf(v1[2], v1[3])));
  for (int o = 32; o; o >>= 1) m = fmaxf(m, __shfl_xor(m, o, 64));
  if ((t & 63) == 0) red[t >> 6] = m;
  __syncthreads();
  m = fmaxf(fmaxf(red[0], red[1]), fmaxf(red[2], red[3]));

  float e[8];
  float s = 0.f;
#pragma unroll
  for (int i = 0; i < 4; ++i) { e[i] = __expf(32.f * (v0[i] - m)); s += e[i]; }
#pragma unroll
  for (int i = 0; i < 4; ++i) { e[4 + i] = __expf(32.f * (v1[i] - m)); s += e[4 + i]; }
  for (int o = 32; o; o >>= 1) s += __shfl_xor(s, o, 64);
  if ((t & 63) == 0) red[4 + (t >> 6)] = s;
  __syncthreads();
  s = red[4] + red[5] + red[6] + red[7];
  const float inv = 1.f / s;
  us4 o0, o1;
#pragma unroll
  for (int i = 0; i < 4; ++i) { o0[i] = f2b(e[i] * inv); o1[i] = f2b(e[4 + i] * inv); }
  *(us4*)&O[t * 4] = o0;
  *(us4*)&O[t * 4 + 1024] = o1;
}

// LayerNorm(C=1024) + ReLU, fp32 in -> bf16 out
__global__ __launch_bounds__(256) void ln_relu(
    const float* __restrict__ X, const float* __restrict__ g,
    const float* __restrict__ b, unsigned short* __restrict__ H) {
  const int row = blockIdx.x;
  const float* x = X + (size_t)row * 1024;
  unsigned short* h = H + (size_t)row * 1024;
  const int t = threadIdx.x;
  __shared__ float red[8];
  f32x4 v = *(const f32x4*)&x[t * 4];
  float s = v[0] + v[1] + v[2] + v[3];
  float q = v[0] * v[0] + v[1] * v[1] + v[2] * v[2] + v[3] * v[3];
  for (int o = 32; o; o >>= 1) {
    s += __shfl_xor(s, o, 64);
    q += __shfl_xor(q, o, 64);
  }
  if ((t & 63) == 0) { red[t >> 6] = s; red[4 + (t >> 6)] = q; }
  __syncthreads();
  s = red[0] + red[1] + red[2] + red[3];
  q = red[4] + red[5] + red[6] + red[7];
  const float mean = s * (1.f / 1024.f);
  const float var = q * (1.f / 1024.f) - mean * mean;
  const float rstd = rsqrtf(var + 1e-5f);
  us4 o;
#pragma unroll
  for (int i = 0; i < 4; ++i) {
    const int c = t * 4 + i;
    const float y = (v[i] - mean) * rstd * g[c] + b[c];
    o[i] = f2b(fmaxf(y, 0.f));
  }
  *(us4*)&h[t * 4] = o;
}

extern "C" void kernel_launch(void* const* d_in, const int* in_sizes, int n_in,
                              void* d_out, int out_size, void* d_ws,
                              size_t ws_size, hipStream_t stream) {
  const float* x = (const float*)d_in[0];
  const float* lfb = (const float*)d_in[1];
  const float* th_w = (const float*)d_in[2];
  const float* th_b = (const float*)d_in[3];
  const float* ph_w = (const float*)d_in[4];
  // ph_b unused: theta.bphi term is per-row constant under softmax
  const float* gi_w = (const float*)d_in[6];
  const float* gi_b = (const float*)d_in[7];
  const float* lng = (const float*)d_in[8];
  const float* lnb = (const float*)d_in[9];
  const float* fc_w = (const float*)d_in[10];
  const float* fc_b = (const float*)d_in[11];
  float* outf = (float*)d_out;
  char* ws = (char*)d_ws;

  const size_t MB = 1048576;
  // Per-batch: logit 8 (holds xs pre-logit / outp post-softmax) + ls 8 +
  // ys 4 (also attn) + giT 4 (also h) = 24 MiB; tail 18 MiB. nb=8 -> 210 MiB.
  int nb = 1;
  for (int cand = 8; cand >= 1; cand >>= 1)
    if ((size_t)cand * 24 * MB + 18 * MB <= ws_size) { nb = cand; break; }

  char* tail = ws + (size_t)nb * 24 * MB;
  unsigned short* tA = (unsigned short*)(tail);           // Wth^T split, 4 MiB
  unsigned short* tB = (unsigned short*)(tail + 4 * MB);  // Wph^T split, 4 MiB
  unsigned short* Gs = (unsigned short*)(tail + 8 * MB);  // G^T split, 4 MiB
  unsigned short* giw = (unsigned short*)(tail + 12 * MB);
  unsigned short* fcw = (unsigned short*)(tail + 14 * MB);
  float* gv = (float*)(tail + 16 * MB);                   // 4 KiB
  float* vb = (float*)(tail + 16 * MB + 65536);           // nb*8 KiB

  dim3 blk(256);
  // ---- prep (once) ----
  transpose_split2<<<dim3(16, 32), blk, 0, stream>>>(th_w, tA, ph_w, tB);
  make_g<<<dim3(256), blk, 0, stream>>>(tB, th_b, gv);
  // G^T = Wph^T.Wth (3-term K=3072). Split-K x8 (z = K-chunk of 384) into fp32
  // partials in the (not-yet-used) main ws region, then reduce+split.
  if (nb >= 2) {
    float* gpart = (float*)ws;  // 32 MiB scratch, free before batch loop
    gemm_bt<MODE_F32><<<dim3(512), blk, 0, stream>>>(
        tB, tA, gpart, nullptr, nullptr, 1024, 1024, 384, 2048, 2048, 1024,
        0, 0, 1048576LL, 0, 2048, 2048, 1024, 1024, 8, 8, 8, 1, 384);
    reduce_g<<<dim3(1024), blk, 0, stream>>>(gpart, Gs);
  } else {
    gemm_bt<MODE_SPLIT><<<dim3(64), blk, 0, stream>>>(
        tB, tA, Gs, nullptr, nullptr, 1024, 1024, 3072, 2048, 2048, 2048,
        0, 0, 0, 0, 2048, 2048, 1024, 1024, 8, 8, 1, 2, 0);
  }
  cvt2_bf16<<<dim3(2048), blk, 0, stream>>>(gi_w, giw, fc_w, fcw);

  for (int b0 = 0; b0 < 8; b0 += nb) {
    unsigned short* xs = (unsigned short*)(ws);             // nb*4 (pre-logit)
    float* logit = (float*)(ws);                            // nb*8
    unsigned short* ls = (unsigned short*)(ws + (size_t)nb * 8 * MB);   // nb*8
    unsigned short* ys = (unsigned short*)(ws + (size_t)nb * 16 * MB);  // nb*4
    unsigned short* giT = (unsigned short*)(ws + (size_t)nb * 20 * MB); // nb*4
    unsigned short* attn = ys;   // ys dead after logits GEMM; stride 2048
    float* outp = (float*)ws;    // logit dead after softmax
    unsigned short* h = giT;     // giT dead after AV GEMM

    const float* xb = x + (size_t)b0 * 1048576;
    const float* lfbb = lfb + (size_t)b0 * 2097152;
    float* ob = outf + (size_t)b0 * 1048576;
    const int Ms = nb * 2048;   // key rows
    const int Mt = nb * 1024;   // query rows
    const int zswz = (nb == 8) ? 1 : 0;

    // split lfb -> ls (+v) and x -> xs in one launch
    split_xlfb<<<dim3(Ms + Mt), blk, 0, stream>>>(lfbb, xb, gv, ls, xs, vb, Ms);
    // giT[b][c][s] = (lfb_h @ gi_w^T + gi_b)^T  (bf16, K=1024); 256^2 32x32,
    // m-slab decode (M-tiles = 8*nb, mbx = nb)
    gemm8<MODE_TRANS><<<dim3(32 * nb), dim3(512), 0, stream>>>(
        ls, giw, giT, gi_b, Ms, 1024, 1024, 2048, 1024, 2048,
        0LL, 0LL, 0LL, 0LL, 1024, 0, 1024, 0, 4, 8 * nb, nb, 2);
    // y = [xh,xl,xh].[Gh,Gh,Gl] -> split hi/lo   [Mt][2048]; m-slab decode
    gemm_bt<MODE_SPLIT><<<dim3(8 * (Mt / 128)), blk, 0, stream>>>(
        xs, Gs, ys, nullptr, nullptr, Mt, 1024, 3072, 2048, 2048, 2048,
        0, 0, 0, 0, 2048, 2048, 1024, 1024, 8, Mt / 128, Mt / 1024, 2, 0);
    // logits = [yh,yl,yh].[lh,lh,ll] + v[s]  (K=3072); 256^2 32x32,
    // z-per-XCD decode (nb=8) or plain (nb<8)
    gemm8<MODE_F32><<<dim3(32 * nb), dim3(512), 0, stream>>>(
        ys, ls, logit, vb, 1024, 2048, 3072, 2048, 2048, 2048,
        2097152LL, 4194304LL, 2097152LL, 2048LL, 2048, 2048, 1024, 1024,
        8, 4, 4, zswz);
    // attn = softmax(32*logits) -> compact bf16 (stride 2048) in ys region
    softmax_rows<<<dim3(Mt), blk, 0, stream>>>(logit, attn);
    // outp = attn @ giT^T (fp32), into logit region; z-per-XCD decode
    gemm_bt<MODE_F32><<<dim3(8 * 8 * nb), blk, 0, stream>>>(
        attn, giT, outp, nullptr, nullptr, 1024, 1024, 2048, 2048, 2048, 1024,
        2097152LL, 2097152LL, 1048576LL, 0, 2048, 0, 2048, 0, 8, 8, 8, zswz, 0);
    // h = relu(LN(outp))
    ln_relu<<<dim3(Mt), blk, 0, stream>>>(outp, lng, lnb, h);
    // out = h @ fc_w^T + fc_b + x; m-slab decode
    gemm_bt<MODE_FINAL><<<dim3(8 * (Mt / 128)), blk, 0, stream>>>(
        h, fcw, ob, fc_b, xb, Mt, 1024, 1024, 1024, 1024, 1024,
        0, 0, 0, 0, 1024, 0, 1024, 0, 8, Mt / 128, Mt / 1024, 2, 0);
  }
}

// Round 9
// 481.954 us; speedup vs baseline: 1.0657x; 1.0657x over previous
//
#include <hip/hip_runtime.h>

// NLBlock fused pipeline for MI355X (gfx950). ALL I/O IS FP32.
// Algebra: logits = x.G.lfb^T + v[s], G = Wth^T.Wph (softmax drops per-row
// constants). Split-precision hi/lo bf16 through G, y, lfb for the x32 logits.
// R17: gemm8 reverted to R13 (2-barrier 256x256x64, 16x16 frags, 0-conflict;
// END vmcnt 8->4 so A(t+1) is provably landed). NEW gemm8B = 256x128x64
// variant of the same schedule for ys/AV/fc: grid 256 = 1 block/CU (their old
// gemm_bt grids were 512 = 2/CU, half the machine's slots), 8 waves 4Mx2N,
// LDS 96 KiB, 0.084 B/MAC LDS traffic. Stage counts: A=4/thread (TOP),
// B=2/thread (MID); END vmcnt(2). gemm_bt kept for G-prep only.

#define BM 128
#define BN 128
#define BK 64

typedef __attribute__((ext_vector_type(8))) short short8;
typedef __attribute__((ext_vector_type(4))) float f32x4;
typedef __attribute__((ext_vector_type(4))) unsigned short us4;

enum { MODE_SPLIT = 0, MODE_TRANS = 1, MODE_F32 = 2, MODE_FINAL = 3 };

__device__ __forceinline__ float b2f(unsigned short u) {
  union { unsigned int i; float f; } x;
  x.i = ((unsigned int)u) << 16;
  return x.f;
}
__device__ __forceinline__ unsigned short f2b(float f) {
  unsigned int u = __float_as_uint(f);
  unsigned int r = (u + 0x7FFFu + ((u >> 16) & 1u)) >> 16;
  return (unsigned short)r;
}

__device__ __forceinline__ void async_cp16(const unsigned short* g,
                                           unsigned short* l) {
  __builtin_amdgcn_global_load_lds(
      (const __attribute__((address_space(1))) void*)g,
      (__attribute__((address_space(3))) void*)l, 16, 0, 0);
}

// Fused: blocks [0,Ms): lfb row -> ls hi/lo + v[row]=dot(lfb[row],g).
//        blocks [Ms,Ms+Mt): x row -> xs hi/lo.
__global__ __launch_bounds__(256) void split_xlfb(
    const float* __restrict__ lfb, const float* __restrict__ x,
    const float* __restrict__ g, unsigned short* __restrict__ ls,
    unsigned short* __restrict__ xs, float* __restrict__ v, int Ms) {
  const int id = blockIdx.x;
  const int t = threadIdx.x;
  const int c = t * 4;
  if (id < Ms) {
    __shared__ float red[4];
    f32x4 xv = *(const f32x4*)&lfb[(size_t)id * 1024 + c];
    f32x4 gg = *(const f32x4*)&g[c];
    us4 hi, lo;
    float s = 0.f;
#pragma unroll
    for (int i = 0; i < 4; ++i) {
      hi[i] = f2b(xv[i]);
      lo[i] = f2b(xv[i] - b2f(hi[i]));
      s += xv[i] * gg[i];
    }
    *(us4*)&ls[(size_t)id * 2048 + c] = hi;
    *(us4*)&ls[(size_t)id * 2048 + 1024 + c] = lo;
    for (int o = 32; o; o >>= 1) s += __shfl_xor(s, o, 64);
    if ((t & 63) == 0) red[t >> 6] = s;
    __syncthreads();
    if (t == 0) v[id] = red[0] + red[1] + red[2] + red[3];
  } else {
    const int r = id - Ms;
    f32x4 xv = *(const f32x4*)&x[(size_t)r * 1024 + c];
    us4 hi, lo;
#pragma unroll
    for (int i = 0; i < 4; ++i) {
      hi[i] = f2b(xv[i]);
      lo[i] = f2b(xv[i] - b2f(hi[i]));
    }
    *(us4*)&xs[(size_t)r * 2048 + c] = hi;
    *(us4*)&xs[(size_t)r * 2048 + 1024 + c] = lo;
  }
}

// two fp32->bf16 conversions in one launch (1 MiB elems each)
__global__ __launch_bounds__(256) void cvt2_bf16(const float* __restrict__ s0,
                                                 unsigned short* __restrict__ d0,
                                                 const float* __restrict__ s1,
                                                 unsigned short* __restrict__ d1) {
  int b = blockIdx.x;
  const float* src = (b < 1024) ? s0 : s1;
  unsigned short* dst = (b < 1024) ? d0 : d1;
  int g = (b & 1023) * 256 + threadIdx.x;
  f32x4 v = *(const f32x4*)&src[g * 4];
  us4 o;
#pragma unroll
  for (int i = 0; i < 4; ++i) o[i] = f2b(v[i]);
  *(us4*)&dst[(size_t)g * 4] = o;
}

// Both weight transposes in one launch: W [1024][1024] fp32 -> T [c][2048]
// bf16 hi|lo with T[c][o]=split(W[o][c]).
__global__ __launch_bounds__(256) void transpose_split2(
    const float* __restrict__ W0, unsigned short* __restrict__ T0,
    const float* __restrict__ W1, unsigned short* __restrict__ T1) {
  __shared__ float tile[64][65];
  const int sel = blockIdx.y >> 4;
  const float* W = sel ? W1 : W0;
  unsigned short* T = sel ? T1 : T0;
  const int bo = (blockIdx.y & 15) * 64;
  const int bc = blockIdx.x * 64;
  const int t = threadIdx.x;
  const int tr = t >> 4;
  const int tc = (t & 15) * 4;
#pragma unroll
  for (int i = 0; i < 4; ++i) {
    f32x4 v = *(const f32x4*)&W[(size_t)(bo + tr + 16 * i) * 1024 + bc + tc];
#pragma unroll
    for (int j = 0; j < 4; ++j) tile[tr + 16 * i][tc + j] = v[j];
  }
  __syncthreads();
#pragma unroll
  for (int i = 0; i < 4; ++i) {
    const int c = bc + tr + 16 * i;
    us4 hi, lo;
#pragma unroll
    for (int j = 0; j < 4; ++j) {
      float v = tile[tc + j][tr + 16 * i];
      hi[j] = f2b(v);
      lo[j] = f2b(v - b2f(hi[j]));
    }
    *(us4*)&T[(size_t)c * 2048 + bo + tc] = hi;
    *(us4*)&T[(size_t)c * 2048 + 1024 + bo + tc] = lo;
  }
}

// g[d] = sum_o Wph[o][d]*bth[o], from tB (= Wph^T split hi/lo). wave per d.
__global__ __launch_bounds__(256) void make_g(
    const unsigned short* __restrict__ tB, const float* __restrict__ bth,
    float* __restrict__ g) {
  const int d = blockIdx.x * 4 + (threadIdx.x >> 6);
  const int lane = threadIdx.x & 63;
  float s = 0.f;
#pragma unroll
  for (int i = 0; i < 4; ++i) {
    const int o0 = lane * 4 + i * 256;
    us4 h = *(const us4*)&tB[(size_t)d * 2048 + o0];
    us4 lo = *(const us4*)&tB[(size_t)d * 2048 + 1024 + o0];
    f32x4 bb = *(const f32x4*)&bth[o0];
#pragma unroll
    for (int j = 0; j < 4; ++j) s += (b2f(h[j]) + b2f(lo[j])) * bb[j];
  }
  for (int o = 32; o; o >>= 1) s += __shfl_xor(s, o, 64);
  if (lane == 0) g[d] = s;
}

// Gs[d][c](hi|lo) = split(sum_z P[z][d][c])   (split-K reduce for G)
__global__ __launch_bounds__(256) void reduce_g(const float* __restrict__ P,
                                                unsigned short* __restrict__ Gs) {
  const int d = blockIdx.x;
  const int c = threadIdx.x * 4;
  f32x4 s = *(const f32x4*)&P[(size_t)d * 1024 + c];
#pragma unroll
  for (int z = 1; z < 8; ++z) {
    f32x4 p = *(const f32x4*)&P[(size_t)z * 1048576 + (size_t)d * 1024 + c];
#pragma unroll
    for (int i = 0; i < 4; ++i) s[i] += p[i];
  }
  us4 hi, lo;
#pragma unroll
  for (int i = 0; i < 4; ++i) {
    hi[i] = f2b(s[i]);
    lo[i] = f2b(s[i] - b2f(hi[i]));
  }
  *(us4*)&Gs[(size_t)d * 2048 + c] = hi;
  *(us4*)&Gs[(size_t)d * 2048 + 1024 + c] = lo;
}

// swz=0: plain (n = id%NBk, m = (id/NBk)%MBk, z = id/(NBk*MBk))
// swz=1: z-per-XCD (z = id&7, r=id>>3, m = r%mbx, n = r/mbx)
// swz=2: m-slab-per-XCD (z=0, m = (id&7)*mbx + r%mbx, n = r/mbx)
// kzoff!=0: z indexes a K-chunk (global k = k0 + z*kzoff; A/B bases unshifted)
template <int MODE>
__global__ __launch_bounds__(256, 4) void gemm_bt(
    const unsigned short* __restrict__ A, const unsigned short* __restrict__ B,
    void* __restrict__ Cout, const float* __restrict__ bias,
    const float* __restrict__ resid, int M, int N, int K, int lda, int ldb,
    int ldc, long long sA, long long sB, long long sC, long long sBias,
    int awrap, int awoff, int bwrap, int bwoff, int NBk, int MBk, int mbx,
    int swz, int kzoff) {
  __shared__ __align__(16) unsigned short As[BM * BK];
  __shared__ __align__(16) unsigned short Bs[BN * BK];

  const int tid = threadIdx.x;
  const int l = tid & 63;
  const int w = tid >> 6;
  const int wm = w >> 1, wn = w & 1;
  const int ln = l & 15, lq = l >> 4;

  int bmi, bni, bzi;
  {
    const int id = blockIdx.x;
    if (swz == 1) {
      bzi = id & 7;
      const int r = id >> 3;
      bmi = r % mbx;
      bni = r / mbx;
    } else if (swz == 2) {
      bzi = 0;
      const int r = id >> 3;
      bmi = (id & 7) * mbx + r % mbx;
      bni = r / mbx;
    } else {
      bni = id % NBk;
      const int rem = id / NBk;
      bmi = rem % MBk;
      bzi = rem / MBk;
    }
  }
  const int bm = bmi * BM;
  const int bn = bni * BN;
  const unsigned short* Ab = A + (size_t)bzi * (size_t)sA;
  const unsigned short* Bb = B + (size_t)bzi * (size_t)sB;
  const float* bz = bias ? bias + (size_t)bzi * (size_t)sBias : nullptr;
  const int kbase = bzi * kzoff;

  const int arow = tid >> 3;
  // Swizzled fetch: lane (rr=l>>3, cc=l&7) fetches k-chunk cc^rr; LDS chunk pc
  // of row r holds k-chunk pc^(r&7). Zero bank conflicts on ds_read_b128.
  const int acol = (((tid & 7) ^ ((tid >> 3) & 7)) * 8);
  const int ldsbase = (tid & 0xC0) * 8;

  f32x4 acc[4][4];
#pragma unroll
  for (int i = 0; i < 4; ++i)
#pragma unroll
    for (int j = 0; j < 4; ++j) acc[i][j] = (f32x4){0.f, 0.f, 0.f, 0.f};

  const int sw = ln & 7;

  for (int k0 = 0; k0 < K; k0 += BK) {
    const int kg = k0 + kbase;
    const int ka = (kg < awrap) ? kg : kg - awoff;
    const int kb = (kg < bwrap) ? kg : kg - bwoff;
#pragma unroll
    for (int it = 0; it < 4; ++it) {
      const int r = it * 32 + arow;
      async_cp16(Ab + (size_t)(bm + r) * lda + ka + acol,
                 &As[it * 2048 + ldsbase]);
    }
#pragma unroll
    for (int it = 0; it < 4; ++it) {
      const int r = it * 32 + arow;
      async_cp16(Bb + (size_t)(bn + r) * ldb + kb + acol,
                 &Bs[it * 2048 + ldsbase]);
    }
    __syncthreads();

#pragma unroll
    for (int ks = 0; ks < 2; ++ks) {
      short8 a[4], b[4];
      const int kof = ((ks * 4 + lq) ^ sw) * 8;
#pragma unroll
      for (int i = 0; i < 4; ++i)
        a[i] = *(const short8*)&As[(wm * 64 + i * 16 + ln) * BK + kof];
#pragma unroll
      for (int j = 0; j < 4; ++j)
        b[j] = *(const short8*)&Bs[(wn * 64 + j * 16 + ln) * BK + kof];
#pragma unroll
      for (int i = 0; i < 4; ++i)
#pragma unroll
        for (int j = 0; j < 4; ++j)
          acc[i][j] = __builtin_amdgcn_mfma_f32_16x16x32_bf16(a[i], b[j],
                                                              acc[i][j], 0, 0, 0);
    }
    __syncthreads();
  }

  float* Cf = (float*)Cout + (size_t)bzi * (size_t)sC;
  unsigned short* Cb = (unsigned short*)Cout + (size_t)bzi * (size_t)sC;

  if constexpr (MODE == MODE_TRANS) {
#pragma unroll
    for (int i = 0; i < 4; ++i) {
      const int gm0 = bm + wm * 64 + i * 16 + lq * 4;
      const int bt = gm0 >> 11;
      const int sr = gm0 & 2047;
#pragma unroll
      for (int j = 0; j < 4; ++j) {
        const int gn = bn + wn * 64 + j * 16 + ln;
        const float bv2 = (bz != nullptr) ? bz[gn] : 0.f;
        us4 o;
#pragma unroll
        for (int r = 0; r < 4; ++r) o[r] = f2b(acc[i][j][r] + bv2);
        *(us4*)&Cb[(size_t)bt * 2097152 + (size_t)gn * 2048 + sr] = o;
      }
    }
  } else {
#pragma unroll
    for (int j = 0; j < 4; ++j) {
      const int gn = bn + wn * 64 + j * 16 + ln;
      const float bv2 = (bz != nullptr) ? bz[gn] : 0.f;
#pragma unroll
      for (int i = 0; i < 4; ++i) {
        const int gm0 = bm + wm * 64 + i * 16 + lq * 4;
#pragma unroll
        for (int r = 0; r < 4; ++r) {
          const int gm = gm0 + r;
          const float v = acc[i][j][r] + bv2;
          if constexpr (MODE == MODE_SPLIT) {
            unsigned short hi = f2b(v);
            Cb[(size_t)gm * ldc + gn] = hi;
            Cb[(size_t)gm * ldc + gn + (ldc >> 1)] = f2b(v - b2f(hi));
          } else if constexpr (MODE == MODE_F32) {
            Cf[(size_t)gm * ldc + gn] = v;
          } else if constexpr (MODE == MODE_FINAL) {
            const size_t idx = (size_t)gm * ldc + gn;
            Cf[idx] = v + resid[idx];
          }
        }
      }
    }
  }
}

// ---- gemm8: 256x256x64 tile, 512 threads (8 waves 2Mx4N), 2 barriers per
// K-tile (R13). LDS A[2][2][8192]+B[2][2][8192] = 128 KiB.
__device__ __forceinline__ void ld8f(const unsigned short* Lb, int roff, int ln,
                                     int lq, int sw, short8* a) {
#pragma unroll
  for (int mi = 0; mi < 4; ++mi)
#pragma unroll
    for (int ks = 0; ks < 2; ++ks)
      a[mi * 2 + ks] = *(const short8*)&Lb[(roff + mi * 16 + ln) * 64 +
                                           (((ks * 4 + lq) ^ sw) * 8)];
}
__device__ __forceinline__ void ld4f(const unsigned short* Lb, int roff, int ln,
                                     int lq, int sw, short8* b) {
#pragma unroll
  for (int ni = 0; ni < 2; ++ni)
#pragma unroll
    for (int ks = 0; ks < 2; ++ks)
      b[ni * 2 + ks] = *(const short8*)&Lb[(roff + ni * 16 + ln) * 64 +
                                           (((ks * 4 + lq) ^ sw) * 8)];
}
template <int MH, int NH>
__device__ __forceinline__ void mfmaQ(f32x4 (&acc)[8][4], const short8* a,
                                      const short8* b) {
  __builtin_amdgcn_s_setprio(1);
#pragma unroll
  for (int mi = 0; mi < 4; ++mi)
#pragma unroll
    for (int ni = 0; ni < 2; ++ni)
#pragma unroll
      for (int ks = 0; ks < 2; ++ks)
        acc[MH * 4 + mi][NH * 2 + ni] = __builtin_amdgcn_mfma_f32_16x16x32_bf16(
            a[mi * 2 + ks], b[ni * 2 + ks], acc[MH * 4 + mi][NH * 2 + ni], 0, 0,
            0);
  __builtin_amdgcn_s_setprio(0);
}

template <int MODE>
__global__ __launch_bounds__(512, 1) void gemm8(
    const unsigned short* __restrict__ A, const unsigned short* __restrict__ B,
    void* __restrict__ Cout, const float* __restrict__ bias, int M, int N,
    int K, int lda, int ldb, int ldc, long long sA, long long sB, long long sC,
    long long sBias, int awrap, int awoff, int bwrap, int bwoff, int NBk,
    int MBk, int mbx, int swz) {
  __shared__ __align__(16) unsigned short Abuf[2][2][8192];
  __shared__ __align__(16) unsigned short Bbuf[2][2][8192];

  const int tid = threadIdx.x;
  const int l = tid & 63;
  const int w = tid >> 6;        // 0..7
  const int wm = w >> 2;         // 0..1 : A half
  const int wn = w & 3;          // 0..3
  const int ln = l & 15, lq = l >> 4;
  const int sw = ln & 7;

  int bmi, bni, bzi;
  {
    const int id = blockIdx.x;
    if (swz == 1) {
      bzi = id & 7;
      const int r = id >> 3;
      bmi = r % mbx;
      bni = r / mbx;
    } else if (swz == 2) {
      bzi = 0;
      const int r = id >> 3;
      bmi = (id & 7) * mbx + r % mbx;
      bni = r / mbx;
    } else {
      bni = id % NBk;
      const int rem = id / NBk;
      bmi = rem % MBk;
      bzi = rem / MBk;
    }
  }
  const int bm = bmi * 256;
  const int bn = bni * 256;
  const unsigned short* Ab = A + (size_t)bzi * (size_t)sA;
  const unsigned short* Bb = B + (size_t)bzi * (size_t)sB;
  const float* bz = bias ? bias + (size_t)bzi * (size_t)sBias : nullptr;

  // staging geometry: thread covers chunk c=j*512+tid of a 128x64 half-tile;
  // row=c>>3, pc=c&7, source k-chunk = pc^(row&7) (same XOR as gemm_bt).
  const int srow = tid >> 3;                                // 0..63
  const int schk = ((tid & 7) ^ ((tid >> 3) & 7)) * 8;      // elem offset
  const int sdst0 = (tid & 448) * 8;                        // wave-uniform base

  auto stageA = [&](int d, int kk) {
#pragma unroll
    for (int half = 0; half < 2; ++half)
#pragma unroll
      for (int j = 0; j < 2; ++j)
        async_cp16(Ab + (size_t)(bm + half * 128 + srow + j * 64) * lda + kk +
                       schk,
                   &Abuf[d][half][sdst0 + j * 4096]);
  };
  auto stageB = [&](int d, int kk) {
#pragma unroll
    for (int half = 0; half < 2; ++half)
#pragma unroll
      for (int j = 0; j < 2; ++j)
        async_cp16(Bb + (size_t)(bn + half * 128 + srow + j * 64) * ldb + kk +
                       schk,
                   &Bbuf[d][half][sdst0 + j * 4096]);
  };
  auto wrapA = [&](int kg) { return (kg < awrap) ? kg : kg - awoff; };
  auto wrapB = [&](int kg) { return (kg < bwrap) ? kg : kg - bwoff; };

  f32x4 acc[8][4];
#pragma unroll
  for (int i = 0; i < 8; ++i)
#pragma unroll
    for (int j = 0; j < 4; ++j) acc[i][j] = (f32x4){0.f, 0.f, 0.f, 0.f};

  const int nt = K >> 6;

  // prologue: A(0),B(0) -> buf0; B(1) -> buf1. vmcnt(4): tile0 landed, B1 in
  // flight.
  stageA(0, wrapA(0));
  stageB(0, wrapB(0));
  if (nt > 1) {
    stageB(1, wrapB(64));
    asm volatile("s_waitcnt vmcnt(4)" : : : "memory");
  } else {
    asm volatile("s_waitcnt vmcnt(0)" : : : "memory");
  }
  __builtin_amdgcn_sched_barrier(0);
  __builtin_amdgcn_s_barrier();

  short8 a0[8], a1[8], b0[4], b1[4];
  const int broff = (wn & 1) * 64;
  const int bhalf = wn >> 1;

  for (int t = 0; t < nt; ++t) {
    const int p = t & 1;
    const unsigned short* LA = &Abuf[p][wm][0];
    const unsigned short* LB = &Bbuf[p][bhalf][0];
    // TOP: issue all reads; stage A(t+1) cross-buf (WAR-safe: END of t-1
    // proved all reads of A[p^1] retired).
    ld8f(LA, 0, ln, lq, sw, a0);
    ld4f(LB, broff, ln, lq, sw, b0);
    ld4f(LB, broff + 32, ln, lq, sw, b1);
    ld8f(LA, 64, ln, lq, sw, a1);
    if (t + 1 < nt) stageA(p ^ 1, wrapA((t + 1) * 64));
    // Q00, Q01: compiler inserts counted lgkmcnt; LDS service hides under MFMA
    mfmaQ<0, 0>(acc, a0, b0);
    mfmaQ<0, 1>(acc, a0, b1);
    // MID: every wave past Q01 has all its TOP reads retired -> B[p] reusable
    asm volatile("s_waitcnt lgkmcnt(0)" : : : "memory");
    __builtin_amdgcn_s_barrier();
    if (t + 2 < nt) stageB(p, wrapB((t + 2) * 64));
    mfmaQ<1, 1>(acc, a1, b1);
    mfmaQ<1, 0>(acc, a1, b0);
    // counted vmcnt(4): keep only B(t+2)'s 4 loads in flight; A(t+1),B(t+1)
    // forced landed for next TOP.
    if (t + 2 < nt) {
      asm volatile("s_waitcnt vmcnt(4)" : : : "memory");
    } else {
      asm volatile("s_waitcnt vmcnt(0)" : : : "memory");
    }
    __builtin_amdgcn_sched_barrier(0);
    __builtin_amdgcn_s_barrier();
  }

  float* Cf = (float*)Cout + (size_t)bzi * (size_t)sC;
  unsigned short* Cb = (unsigned short*)Cout;

  if constexpr (MODE == MODE_TRANS) {
#pragma unroll
    for (int mi = 0; mi < 8; ++mi) {
      const int gm0 = bm + wm * 128 + mi * 16 + lq * 4;
      const int bt = gm0 >> 11;
      const int sr = gm0 & 2047;
#pragma unroll
      for (int ni = 0; ni < 4; ++ni) {
        const int gn = bn + wn * 64 + ni * 16 + ln;
        const float bv2 = (bz != nullptr) ? bz[gn] : 0.f;
        us4 o;
#pragma unroll
        for (int r = 0; r < 4; ++r) o[r] = f2b(acc[mi][ni][r] + bv2);
        *(us4*)&Cb[(size_t)bt * 2097152 + (size_t)gn * 2048 + sr] = o;
      }
    }
  } else {  // MODE_F32
#pragma unroll
    for (int ni = 0; ni < 4; ++ni) {
      const int gn = bn + wn * 64 + ni * 16 + ln;
      const float bv2 = (bz != nullptr) ? bz[gn] : 0.f;
#pragma unroll
      for (int mi = 0; mi < 8; ++mi) {
        const int gm0 = bm + wm * 128 + mi * 16 + lq * 4;
#pragma unroll
        for (int r = 0; r < 4; ++r)
          Cf[(size_t)(gm0 + r) * ldc + gn] = acc[mi][ni][r] + bv2;
      }
    }
  }
}

// ---- gemm8B: 256x128x64 tile, 512 threads (8 waves 4Mx2N, wave-tile 64x64),
// same 2-barrier ledger as gemm8 with B stage halved: TOP[16 ds_reads +
// stageA(t+1) 4/thr] MFMA ks0 | lgkm(0) MID bar stageB(t+2) 2/thr MFMA ks1
// vmcnt(2) END bar. LDS A[2][2][8192]+B[2][8192] = 96 KiB. grid = 1 block/CU
// for ys/AV/fc shapes. Fragment/epilogue geometry identical to gemm_bt.
template <int MODE>
__global__ __launch_bounds__(512, 1) void gemm8B(
    const unsigned short* __restrict__ A, const unsigned short* __restrict__ B,
    void* __restrict__ Cout, const float* __restrict__ bias,
    const float* __restrict__ resid, int M, int N, int K, int lda, int ldb,
    int ldc, long long sA, long long sB, long long sC, long long sBias,
    int awrap, int awoff, int bwrap, int bwoff, int NBk, int MBk, int mbx,
    int swz) {
  __shared__ __align__(16) unsigned short Abuf[2][2][8192];
  __shared__ __align__(16) unsigned short Bbuf[2][8192];

  const int tid = threadIdx.x;
  const int l = tid & 63;
  const int w = tid >> 6;        // 0..7
  const int wm = w >> 1;         // 0..3 : 64-row band of the 256-row tile
  const int wn = w & 1;          // 0..1 : 64-col band of the 128-col tile
  const int ln = l & 15, lq = l >> 4;
  const int sw = ln & 7;

  int bmi, bni, bzi;
  {
    const int id = blockIdx.x;
    if (swz == 1) {
      bzi = id & 7;
      const int r = id >> 3;
      bmi = r % mbx;
      bni = r / mbx;
    } else if (swz == 2) {
      bzi = 0;
      const int r = id >> 3;
      bmi = (id & 7) * mbx + r % mbx;
      bni = r / mbx;
    } else {
      bni = id % NBk;
      const int rem = id / NBk;
      bmi = rem % MBk;
      bzi = rem / MBk;
    }
  }
  const int bm = bmi * 256;
  const int bn = bni * 128;
  const unsigned short* Ab = A + (size_t)bzi * (size_t)sA;
  const unsigned short* Bb = B + (size_t)bzi * (size_t)sB;
  const float* bz = bias ? bias + (size_t)bzi * (size_t)sBias : nullptr;

  const int srow = tid >> 3;                                // 0..63
  const int schk = ((tid & 7) ^ ((tid >> 3) & 7)) * 8;      // elem offset
  const int sdst0 = (tid & 448) * 8;                        // wave-uniform base

  auto stageA = [&](int d, int kk) {
#pragma unroll
    for (int half = 0; half < 2; ++half)
#pragma unroll
      for (int j = 0; j < 2; ++j)
        async_cp16(Ab + (size_t)(bm + half * 128 + srow + j * 64) * lda + kk +
                       schk,
                   &Abuf[d][half][sdst0 + j * 4096]);
  };
  auto stageB = [&](int d, int kk) {
#pragma unroll
    for (int j = 0; j < 2; ++j)
      async_cp16(Bb + (size_t)(bn + srow + j * 64) * ldb + kk + schk,
                 &Bbuf[d][sdst0 + j * 4096]);
  };
  auto wrapA = [&](int kg) { return (kg < awrap) ? kg : kg - awoff; };
  auto wrapB = [&](int kg) { return (kg < bwrap) ? kg : kg - bwoff; };

  f32x4 acc[4][4];
#pragma unroll
  for (int i = 0; i < 4; ++i)
#pragma unroll
    for (int j = 0; j < 4; ++j) acc[i][j] = (f32x4){0.f, 0.f, 0.f, 0.f};

  const int nt = K >> 6;

  // prologue: A(0)[4/thr]+B(0)[2] -> buf0; B(1)[2] -> buf1. vmcnt(2): A0,B0
  // landed, B1 in flight.
  stageA(0, wrapA(0));
  stageB(0, wrapB(0));
  if (nt > 1) {
    stageB(1, wrapB(64));
    asm volatile("s_waitcnt vmcnt(2)" : : : "memory");
  } else {
    asm volatile("s_waitcnt vmcnt(0)" : : : "memory");
  }
  __builtin_amdgcn_sched_barrier(0);
  __builtin_amdgcn_s_barrier();

  const int ahalf = wm >> 1;
  const int aroff = (wm & 1) * 64;
  const int broff = wn * 64;

  for (int t = 0; t < nt; ++t) {
    const int p = t & 1;
    const unsigned short* LA = &Abuf[p][ahalf][0];
    const unsigned short* LB = &Bbuf[p][0];
    short8 a[2][4], b[2][4];
    // TOP: all 16 reads (ks0,ks1); stage A(t+1) cross-buf (WAR-safe: END of
    // t-1 proved all reads of A[p^1] retired at t-1's MID lgkm(0)+barrier).
#pragma unroll
    for (int ks = 0; ks < 2; ++ks) {
      const int kof = ((ks * 4 + lq) ^ sw) * 8;
#pragma unroll
      for (int i = 0; i < 4; ++i)
        a[ks][i] = *(const short8*)&LA[(aroff + i * 16 + ln) * 64 + kof];
#pragma unroll
      for (int j = 0; j < 4; ++j)
        b[ks][j] = *(const short8*)&LB[(broff + j * 16 + ln) * 64 + kof];
    }
    if (t + 1 < nt) stageA(p ^ 1, wrapA((t + 1) * 64));
    // MFMA ks0 (compiler paces lgkmcnt; ks1 reads drain under these)
    __builtin_amdgcn_s_setprio(1);
#pragma unroll
    for (int i = 0; i < 4; ++i)
#pragma unroll
      for (int j = 0; j < 4; ++j)
        acc[i][j] = __builtin_amdgcn_mfma_f32_16x16x32_bf16(a[0][i], b[0][j],
                                                            acc[i][j], 0, 0, 0);
    __builtin_amdgcn_s_setprio(0);
    // MID: all TOP reads retired chip-wide -> B[p] reusable
    asm volatile("s_waitcnt lgkmcnt(0)" : : : "memory");
    __builtin_amdgcn_s_barrier();
    if (t + 2 < nt) stageB(p, wrapB((t + 2) * 64));
    __builtin_amdgcn_s_setprio(1);
#pragma unroll
    for (int i = 0; i < 4; ++i)
#pragma unroll
      for (int j = 0; j < 4; ++j)
        acc[i][j] = __builtin_amdgcn_mfma_f32_16x16x32_bf16(a[1][i], b[1][j],
                                                            acc[i][j], 0, 0, 0);
    __builtin_amdgcn_s_setprio(0);
    // END vmcnt(2): keep only B(t+2)'s 2 loads in flight; B(t+1),A(t+1)
    // forced landed before next TOP reads them.
    if (t + 2 < nt) {
      asm volatile("s_waitcnt vmcnt(2)" : : : "memory");
    } else {
      asm volatile("s_waitcnt vmcnt(0)" : : : "memory");
    }
    __builtin_amdgcn_sched_barrier(0);
    __builtin_amdgcn_s_barrier();
  }

  float* Cf = (float*)Cout + (size_t)bzi * (size_t)sC;
  unsigned short* Cb = (unsigned short*)Cout + (size_t)bzi * (size_t)sC;

#pragma unroll
  for (int j = 0; j < 4; ++j) {
    const int gn = bn + wn * 64 + j * 16 + ln;
    const float bv2 = (bz != nullptr) ? bz[gn] : 0.f;
#pragma unroll
    for (int i = 0; i < 4; ++i) {
      const int gm0 = bm + wm * 64 + i * 16 + lq * 4;
#pragma unroll
      for (int r = 0; r < 4; ++r) {
        const int gm = gm0 + r;
        const float v = acc[i][j][r] + bv2;
        if constexpr (MODE == MODE_SPLIT) {
          unsigned short hi = f2b(v);
          Cb[(size_t)gm * ldc + gn] = hi;
          Cb[(size_t)gm * ldc + gn + (ldc >> 1)] = f2b(v - b2f(hi));
        } else if constexpr (MODE == MODE_F32) {
          Cf[(size_t)gm * ldc + gn] = v;
        } else if constexpr (MODE == MODE_FINAL) {
          const size_t idx = (size_t)gm * ldc + gn;
          Cf[idx] = v + resid[idx];
        }
      }
    }
  }
}

// softmax over 2048 fp32 cols, scale 32 -> bf16 attn (compact, stride 2048)
__global__ __launch_bounds__(256) void softmax_rows(
    const float* __restrict__ logit, unsigned short* __restrict__ attn) {
  const int row = blockIdx.x;
  const float* L = logit + (size_t)row * 2048;
  unsigned short* O = attn + (size_t)row * 2048;
  const int t = threadIdx.x;
  __shared__ float red[8];

  f32x4 v0 = *(const f32x4*)&L[t * 4];
  f32x4 v1 = *(const f32x4*)&L[t * 4 + 1024];
  float m = fmaxf(fmaxf(fmaxf(v0[0], v0[1]), fmaxf(v0[2], v0[3])),
                  fmaxf(fmaxf(v1[0], v1[1]), fmaxf(v1[2], v1[3])));
  for (int o = 32; o; o >>= 1) m = fmaxf(m, __shfl_xor(m, o, 64));
  if ((t & 63) == 0) red[t >> 6] = m;
  __syncthreads();
  m = fmaxf(fmaxf(red[0], red[1]), fmaxf(red[2], red[3]));

  float e[8];
  float s = 0.f;
#pragma unroll
  for (int i = 0; i < 4; ++i) { e[i] = __expf(32.f * (v0[i] - m)); s += e[i]; }
#pragma unroll
  for (int i = 0; i < 4; ++i) { e[4 + i] = __expf(32.f * (v1[i] - m)); s += e[4 + i]; }
  for (int o = 32; o; o >>= 1) s += __shfl_xor(s, o, 64);
  if ((t & 63) == 0) red[4 + (t >> 6)] = s;
  __syncthreads();
  s = red[4] + red[5] + red[6] + red[7];
  const float inv = 1.f / s;
  us4 o0, o1;
#pragma unroll
  for (int i = 0; i < 4; ++i) { o0[i] = f2b(e[i] * inv); o1[i] = f2b(e[4 + i] * inv); }
  *(us4*)&O[t * 4] = o0;
  *(us4*)&O[t * 4 + 1024] = o1;
}

// LayerNorm(C=1024) + ReLU, fp32 in -> bf16 out
__global__ __launch_bounds__(256) void ln_relu(
    const float* __restrict__ X, const float* __restrict__ g,
    const float* __restrict__ b, unsigned short* __restrict__ H) {
  const int row = blockIdx.x;
  const float* x = X + (size_t)row * 1024;
  unsigned short* h = H + (size_t)row * 1024;
  const int t = threadIdx.x;
  __shared__ float red[8];
  f32x4 v = *(const f32x4*)&x[t * 4];
  float s = v[0] + v[1] + v[2] + v[3];
  float q = v[0] * v[0] + v[1] * v[1] + v[2] * v[2] + v[3] * v[3];
  for (int o = 32; o; o >>= 1) {
    s += __shfl_xor(s, o, 64);
    q += __shfl_xor(q, o, 64);
  }
  if ((t & 63) == 0) { red[t >> 6] = s; red[4 + (t >> 6)] = q; }
  __syncthreads();
  s = red[0] + red[1] + red[2] + red[3];
  q = red[4] + red[5] + red[6] + red[7];
  const float mean = s * (1.f / 1024.f);
  const float var = q * (1.f / 1024.f) - mean * mean;
  const float rstd = rsqrtf(var + 1e-5f);
  us4 o;
#pragma unroll
  for (int i = 0; i < 4; ++i) {
    const int c = t * 4 + i;
    const float y = (v[i] - mean) * rstd * g[c] + b[c];
    o[i] = f2b(fmaxf(y, 0.f));
  }
  *(us4*)&h[t * 4] = o;
}

extern "C" void kernel_launch(void* const* d_in, const int* in_sizes, int n_in,
                              void* d_out, int out_size, void* d_ws,
                              size_t ws_size, hipStream_t stream) {
  const float* x = (const float*)d_in[0];
  const float* lfb = (const float*)d_in[1];
  const float* th_w = (const float*)d_in[2];
  const float* th_b = (const float*)d_in[3];
  const float* ph_w = (const float*)d_in[4];
  // ph_b unused: theta.bphi term is per-row constant under softmax
  const float* gi_w = (const float*)d_in[6];
  const float* gi_b = (const float*)d_in[7];
  const float* lng = (const float*)d_in[8];
  const float* lnb = (const float*)d_in[9];
  const float* fc_w = (const float*)d_in[10];
  const float* fc_b = (const float*)d_in[11];
  float* outf = (float*)d_out;
  char* ws = (char*)d_ws;

  const size_t MB = 1048576;
  // Per-batch: logit 8 (holds xs pre-logit / outp post-softmax) + ls 8 +
  // ys 4 (also attn) + giT 4 (also h) = 24 MiB; tail 18 MiB. nb=8 -> 210 MiB.
  int nb = 1;
  for (int cand = 8; cand >= 1; cand >>= 1)
    if ((size_t)cand * 24 * MB + 18 * MB <= ws_size) { nb = cand; break; }

  char* tail = ws + (size_t)nb * 24 * MB;
  unsigned short* tA = (unsigned short*)(tail);           // Wth^T split, 4 MiB
  unsigned short* tB = (unsigned short*)(tail + 4 * MB);  // Wph^T split, 4 MiB
  unsigned short* Gs = (unsigned short*)(tail + 8 * MB);  // G^T split, 4 MiB
  unsigned short* giw = (unsigned short*)(tail + 12 * MB);
  unsigned short* fcw = (unsigned short*)(tail + 14 * MB);
  float* gv = (float*)(tail + 16 * MB);                   // 4 KiB
  float* vb = (float*)(tail + 16 * MB + 65536);           // nb*8 KiB

  dim3 blk(256);
  // ---- prep (once) ----
  transpose_split2<<<dim3(16, 32), blk, 0, stream>>>(th_w, tA, ph_w, tB);
  make_g<<<dim3(256), blk, 0, stream>>>(tB, th_b, gv);
  // G^T = Wph^T.Wth (3-term K=3072). Split-K x8 (z = K-chunk of 384) into fp32
  // partials in the (not-yet-used) main ws region, then reduce+split.
  if (nb >= 2) {
    float* gpart = (float*)ws;  // 32 MiB scratch, free before batch loop
    gemm_bt<MODE_F32><<<dim3(512), blk, 0, stream>>>(
        tB, tA, gpart, nullptr, nullptr, 1024, 1024, 384, 2048, 2048, 1024,
        0, 0, 1048576LL, 0, 2048, 2048, 1024, 1024, 8, 8, 8, 1, 384);
    reduce_g<<<dim3(1024), blk, 0, stream>>>(gpart, Gs);
  } else {
    gemm_bt<MODE_SPLIT><<<dim3(64), blk, 0, stream>>>(
        tB, tA, Gs, nullptr, nullptr, 1024, 1024, 3072, 2048, 2048, 2048,
        0, 0, 0, 0, 2048, 2048, 1024, 1024, 8, 8, 1, 2, 0);
  }
  cvt2_bf16<<<dim3(2048), blk, 0, stream>>>(gi_w, giw, fc_w, fcw);

  for (int b0 = 0; b0 < 8; b0 += nb) {
    unsigned short* xs = (unsigned short*)(ws);             // nb*4 (pre-logit)
    float* logit = (float*)(ws);                            // nb*8
    unsigned short* ls = (unsigned short*)(ws + (size_t)nb * 8 * MB);   // nb*8
    unsigned short* ys = (unsigned short*)(ws + (size_t)nb * 16 * MB);  // nb*4
    unsigned short* giT = (unsigned short*)(ws + (size_t)nb * 20 * MB); // nb*4
    unsigned short* attn = ys;   // ys dead after logits GEMM; stride 2048
    float* outp = (float*)ws;    // logit dead after softmax
    unsigned short* h = giT;     // giT dead after AV GEMM

    const float* xb = x + (size_t)b0 * 1048576;
    const float* lfbb = lfb + (size_t)b0 * 2097152;
    float* ob = outf + (size_t)b0 * 1048576;
    const int Ms = nb * 2048;   // key rows
    const int Mt = nb * 1024;   // query rows
    const int zswz = (nb == 8) ? 1 : 0;
    const int mswz = (nb == 8) ? 2 : 0;

    // split lfb -> ls (+v) and x -> xs in one launch
    split_xlfb<<<dim3(Ms + Mt), blk, 0, stream>>>(lfbb, xb, gv, ls, xs, vb, Ms);
    // giT[b][c][s] = (lfb_h @ gi_w^T + gi_b)^T  (bf16, K=1024); 256^2 2-barrier
    // pipeline, m-slab decode (M-tiles = 8*nb, mbx = nb)
    gemm8<MODE_TRANS><<<dim3(32 * nb), dim3(512), 0, stream>>>(
        ls, giw, giT, gi_b, Ms, 1024, 1024, 2048, 1024, 2048,
        0LL, 0LL, 0LL, 0LL, 1024, 0, 1024, 0, 4, 8 * nb, nb, 2);
    // y = [xh,xl,xh].[Gh,Gh,Gl] -> split hi/lo   [Mt][2048]; gemm8B 256x128,
    // grid (Mt/256)*8 = 1 block/CU at nb=8; m-slab decode (mbx = Mt/2048)
    gemm8B<MODE_SPLIT><<<dim3((Mt / 256) * 8), dim3(512), 0, stream>>>(
        xs, Gs, ys, nullptr, nullptr, Mt, 1024, 3072, 2048, 2048, 2048,
        0LL, 0LL, 0LL, 0LL, 2048, 2048, 1024, 1024, 8, Mt / 256,
        (nb == 8) ? (Mt / 2048) : 0, mswz);
    // logits = [yh,yl,yh].[lh,lh,ll] + v[s]  (K=3072); 256^2 2-barrier
    // pipeline, z-per-XCD decode (nb=8) or plain (nb<8)
    gemm8<MODE_F32><<<dim3(32 * nb), dim3(512), 0, stream>>>(
        ys, ls, logit, vb, 1024, 2048, 3072, 2048, 2048, 2048,
        2097152LL, 4194304LL, 2097152LL, 2048LL, 2048, 2048, 1024, 1024,
        8, 4, 4, zswz);
    // attn = softmax(32*logits) -> compact bf16 (stride 2048) in ys region
    softmax_rows<<<dim3(Mt), blk, 0, stream>>>(logit, attn);
    // outp = attn @ giT^T (fp32), into logit region; gemm8B 256x128,
    // grid 32*nb; z-per-XCD decode (mbx = 1024/256 = 4)
    gemm8B<MODE_F32><<<dim3(32 * nb), dim3(512), 0, stream>>>(
        attn, giT, outp, nullptr, nullptr, 1024, 1024, 2048, 2048, 2048, 1024,
        2097152LL, 2097152LL, 1048576LL, 0LL, 2048, 0, 2048, 0, 8, 4, 4, zswz);
    // h = relu(LN(outp))
    ln_relu<<<dim3(Mt), blk, 0, stream>>>(outp, lng, lnb, h);
    // out = h @ fc_w^T + fc_b + x; gemm8B 256x128, grid (Mt/256)*8; m-slab
    gemm8B<MODE_FINAL><<<dim3((Mt / 256) * 8), dim3(512), 0, stream>>>(
        h, fcw, ob, fc_b, xb, Mt, 1024, 1024, 1024, 1024, 1024,
        0LL, 0LL, 0LL, 0LL, 1024, 0, 1024, 0, 8, Mt / 256,
        (nb == 8) ? (Mt / 2048) : 0, mswz);
  }
}